// Round 13
// baseline (950.828 us; speedup 1.0000x reference)
//
#include <hip/hip_runtime.h>
#include <cmath>

#define NTOK 65536
#define DMOD 1024
#define NEXP 64
#define TOPK 8
#define BTOK 64                  // tokens per block
#define KCH  32                  // k-chunk per LDS buffer
#define NCH  (DMOD / KCH)        // 32 chunks

typedef __attribute__((address_space(3))) unsigned int* lds_ptr_t;
typedef const __attribute__((address_space(1))) unsigned int* gbl_ptr_t;

// fire-and-forget global->LDS DMA, 16B per lane (dest = uniform base + lane*16)
__device__ __forceinline__ void gload16(const float* gsrc, float* ldst) {
    __builtin_amdgcn_global_load_lds((gbl_ptr_t)gsrc, (lds_ptr_t)ldst, 16, 0, 0);
}

__device__ __forceinline__ float4 lds_read4(const float* base, unsigned boff) {
    return *reinterpret_cast<const float4*>(reinterpret_cast<const char*>(base) + boff);
}

// token_mask may arrive as 1-byte bool or int32; sniff from the first word.
__device__ __forceinline__ bool tok_mask(const void* tm, int t, int mmode) {
    return mmode == 0 ? (((const unsigned char*)tm)[t] != 0)
                      : (((const unsigned int*)tm)[t] != 0u);
}

__global__ __launch_bounds__(256, 3)
void router_v13(const float* __restrict__ h,
                const float* __restrict__ W,
                const void* __restrict__ tmask,
                float* __restrict__ out)
{
    __shared__ __align__(16) float h_s[2][BTOK][KCH];   // 16 KB, XOR-swizzled chunks
    __shared__ __align__(16) float w_s[2][NEXP][KCH];   // 16 KB, XOR-swizzled chunks
    __shared__ __align__(16) float ls[64][65];          // 16.6 KB logits tile
    __shared__ float sm_m0[64], sm_inv[64];
    __shared__ unsigned long long mb[64];

    const int tid  = threadIdx.x;
    const int lane = tid & 63;
    const int wave = __builtin_amdgcn_readfirstlane(tid >> 6);
    const int tt   = tid & 15;                // token group: rows 4tt..4tt+3
    const int ee   = tid >> 4;                // expert group: rows 4ee..4ee+3
    const int t0   = blockIdx.x * BTOK;

    const unsigned int mw = *(const unsigned int*)tmask;
    const int mmode = (mw == 0x01010101u) ? 0 : 1;

    // ---- staging source addresses (per-lane, swizzled chunk col) ----
    // call q covers LDS rows wave*16+8q .. +7; lane -> row base+(lane>>3), chunk c'=lane&7
    const int r0 = wave * 16 + (lane >> 3);
    const int r1 = r0 + 8;
    const int c0 = (lane & 7) ^ ((r0 >> 2) & 7);   // source chunk for dest c'=lane&7
    const int c1 = (lane & 7) ^ ((r1 >> 2) & 7);
    const float* hsrc0 = h + (size_t)(t0 + r0) * DMOD + c0 * 4;
    const float* hsrc1 = h + (size_t)(t0 + r1) * DMOD + c1 * 4;
    const float* wsrc0 = W + ((size_t)r0 << 10) + c0 * 4;
    const float* wsrc1 = W + ((size_t)r1 << 10) + c1 * 4;

#define STAGE(buf, kc)                                              \
    do {                                                            \
        gload16(hsrc0 + (kc), &h_s[buf][wave * 16][0]);             \
        gload16(hsrc1 + (kc), &h_s[buf][wave * 16 + 8][0]);         \
        gload16(wsrc0 + (kc), &w_s[buf][wave * 16][0]);             \
        gload16(wsrc1 + (kc), &w_s[buf][wave * 16 + 8][0]);         \
    } while (0)

    // ---- strict sequential fp32 FMA per output, k ascending (np-matching) ----
    float acc[4][4];
#pragma unroll
    for (int i = 0; i < 4; ++i)
#pragma unroll
        for (int j = 0; j < 4; ++j) acc[i][j] = 0.f;

    // per-thread LDS read byte-offsets (row*128 + swz*16); read applies ^ (k4<<4)
    unsigned hoff[4], woff[4];
#pragma unroll
    for (int i = 0; i < 4; ++i) hoff[i] = (unsigned)((tt * 4 + i) * (KCH * 4) + ((tt & 7) << 4));
#pragma unroll
    for (int j = 0; j < 4; ++j) woff[j] = (unsigned)((ee * 4 + j) * (KCH * 4) + ((ee & 7) << 4));

#define COMPUTE(buf)                                                               \
    do {                                                                           \
        const float* hb = &h_s[buf][0][0];                                         \
        const float* wb = &w_s[buf][0][0];                                         \
        _Pragma("unroll")                                                          \
        for (int k4 = 0; k4 < KCH / 4; ++k4) {                                     \
            float4 hv[4], wv[4];                                                   \
            _Pragma("unroll")                                                      \
            for (int i = 0; i < 4; ++i) hv[i] = lds_read4(hb, hoff[i] ^ (k4 << 4));\
            _Pragma("unroll")                                                      \
            for (int j = 0; j < 4; ++j) wv[j] = lds_read4(wb, woff[j] ^ (k4 << 4));\
            _Pragma("unroll")                                                      \
            for (int i = 0; i < 4; ++i) {                                          \
                _Pragma("unroll")                                                  \
                for (int j = 0; j < 4; ++j) {                                      \
                    float a = acc[i][j];                                           \
                    a = fmaf(hv[i].x, wv[j].x, a);                                 \
                    a = fmaf(hv[i].y, wv[j].y, a);                                 \
                    a = fmaf(hv[i].z, wv[j].z, a);                                 \
                    a = fmaf(hv[i].w, wv[j].w, a);                                 \
                    acc[i][j] = a;                                                 \
                }                                                                  \
            }                                                                      \
        }                                                                          \
    } while (0)

    // ---- T3 2-phase pipeline: prefetch chunk c+1 via global_load_lds, compute c ----
    STAGE(0, 0);
    __syncthreads();                          // drains vmcnt: buf0 ready

    for (int c = 0; c < NCH; c += 2) {
        if (c + 1 < NCH) STAGE(1, (c + 1) * KCH);   // in flight during compute
        COMPUTE(0);
        __syncthreads();                      // waves done with buf0; buf1 landed
        if (c + 2 < NCH) STAGE(0, (c + 2) * KCH);
        COMPUTE(1);
        __syncthreads();
    }

    // ---- stage logits ----
#pragma unroll
    for (int i = 0; i < 4; ++i)
#pragma unroll
        for (int j = 0; j < 4; ++j)
            ls[tt * 4 + i][ee * 4 + j] = acc[i][j];

    __syncthreads();

    const size_t P = (size_t)NTOK * NEXP;
    float* __restrict__ o_mask = out;
    float* __restrict__ o_prob = out + P;
    float* __restrict__ o_lc   = out + 2 * P;
    float* __restrict__ o_lsl  = out + 3 * P;
    const size_t base = (size_t)t0 * NEXP;

    // ---- vectorized writes of logits_clean / logits_sel (float4) ----
#pragma unroll
    for (int p = 0; p < 4; ++p) {
        const int g  = p * 256 + tid;         // float4 index
        const int t  = g >> 4;
        const int e4 = (g & 15) * 4;
        const float4 lv = *reinterpret_cast<const float4*>(&ls[t][e4]);
        const bool tmt = tok_mask(tmask, t0 + t, mmode);
        float4 sv;
        sv.x = tmt ? lv.x : -INFINITY;
        sv.y = tmt ? lv.y : -INFINITY;
        sv.z = tmt ? lv.z : -INFINITY;
        sv.w = tmt ? lv.w : -INFINITY;
        *reinterpret_cast<float4*>(&o_lc[base + (size_t)g * 4])  = lv;
        *reinterpret_cast<float4*>(&o_lsl[base + (size_t)g * 4]) = sv;
    }

    // ---- epilogue: wave0, one token per lane; 8-pass selection-sort top-k ----
    if (wave == 0) {
        const int lt = lane;
        const bool tm = tok_mask(tmask, t0 + lt, mmode);

        unsigned long long bits = 0ULL;
        float m0 = -INFINITY;
        for (int r = 0; r < TOPK; ++r) {
            float bv = -INFINITY; int bi = 0;
            for (int e = 0; e < 64; ++e) {
                if ((bits >> e) & 1ULL) continue;
                const float x = ls[lt][e];
                if (x > bv) { bv = x; bi = e; }
            }
            bits |= 1ULL << bi;
            if (r == 0) m0 = bv;
        }

        float ssum = 0.f;
        for (int e = 0; e < 64; ++e)
            if ((bits >> e) & 1ULL) ssum += expf(ls[lt][e] - m0);

        sm_m0[lt]  = m0;
        sm_inv[lt] = 1.0f / ssum;
        mb[lt] = tm ? bits : 0ULL;            // mb==0 encodes masked token
    }

    __syncthreads();

    // ---- vectorized writes of probs / mask (float4) ----
#pragma unroll
    for (int p = 0; p < 4; ++p) {
        const int g  = p * 256 + tid;
        const int t  = g >> 4;
        const int e4 = (g & 15) * 4;
        const float4 lv = *reinterpret_cast<const float4*>(&ls[t][e4]);
        const unsigned long long bt = mb[t];
        const float m0 = sm_m0[t], inv = sm_inv[t];
        float4 pv, mv;
        const bool s0 = (bt >> (e4 + 0)) & 1ULL;
        const bool s1 = (bt >> (e4 + 1)) & 1ULL;
        const bool s2 = (bt >> (e4 + 2)) & 1ULL;
        const bool s3 = (bt >> (e4 + 3)) & 1ULL;
        pv.x = s0 ? expf(lv.x - m0) * inv : 0.f;
        pv.y = s1 ? expf(lv.y - m0) * inv : 0.f;
        pv.z = s2 ? expf(lv.z - m0) * inv : 0.f;
        pv.w = s3 ? expf(lv.w - m0) * inv : 0.f;
        mv.x = s0 ? 1.f : 0.f;
        mv.y = s1 ? 1.f : 0.f;
        mv.z = s2 ? 1.f : 0.f;
        mv.w = s3 ? 1.f : 0.f;
        *reinterpret_cast<float4*>(&o_prob[base + (size_t)g * 4]) = pv;
        *reinterpret_cast<float4*>(&o_mask[base + (size_t)g * 4]) = mv;
    }
}

extern "C" void kernel_launch(void* const* d_in, const int* in_sizes, int n_in,
                              void* d_out, int out_size, void* d_ws, size_t ws_size,
                              hipStream_t stream)
{
    const float* h = (const float*)d_in[0];
    const float* W = (const float*)d_in[1];
    const void*  tmask = (const void*)d_in[2];
    float* out = (float*)d_out;

    hipLaunchKernelGGL(router_v13, dim3(NTOK / BTOK), dim3(256), 0, stream,
                       h, W, tmask, out);
}

// Round 14
// 696.177 us; speedup vs baseline: 1.3658x; 1.3658x over previous
//
#include <hip/hip_runtime.h>
#include <cmath>

#define NTOK 65536
#define DMOD 1024
#define NEXP 64
#define TOPK 8
#define BTOK 64                  // tokens per block
#define KCH  32                  // k-chunk staged in LDS
#define NCH  (DMOD / KCH)        // 32 chunks
#define TSTR 33                  // tile row stride (odd -> 2-way max on reads)
#define LSTR 65                  // logits row stride

// token_mask may arrive as 1-byte bool or int32; sniff from the first word.
__device__ __forceinline__ bool tok_mask(const void* tm, int t, int mmode) {
    return mmode == 0 ? (((const unsigned char*)tm)[t] != 0)
                      : (((const unsigned int*)tm)[t] != 0u);
}

__global__ __launch_bounds__(256, 8)
void router_v14(const float* __restrict__ h,
                const float* __restrict__ W,
                const void* __restrict__ tmask,
                float* __restrict__ out)
{
    // h tile + W tile; the whole region is reused as the logits tile ls[64][65]
    __shared__ __align__(16) float smem[2 * 64 * TSTR];   // 16.9 KB
    __shared__ float sm_m0[BTOK], sm_inv[BTOK];
    __shared__ unsigned long long mb[BTOK];

    float (*h_s)[TSTR] = reinterpret_cast<float(*)[TSTR]>(smem);
    float (*w_s)[TSTR] = reinterpret_cast<float(*)[TSTR]>(smem + 64 * TSTR);
    float (*ls)[LSTR]  = reinterpret_cast<float(*)[LSTR]>(smem);   // epilogue alias

    const int tid  = threadIdx.x;
    const int lane = tid & 63;
    const int wave = tid >> 6;
    const int tt   = tid & 15;                // token group: rows 4tt..4tt+3
    const int ee   = tid >> 4;                // expert group: rows 4ee..4ee+3
    const int t0   = blockIdx.x * BTOK;

    const unsigned int mw = *(const unsigned int*)tmask;
    const int mmode = (mw == 0x01010101u) ? 0 : 1;

    // strict sequential fp32 FMA per output, k ascending (np-ref-matching order)
    float acc[4][4];
#pragma unroll
    for (int i = 0; i < 4; ++i)
#pragma unroll
        for (int j = 0; j < 4; ++j) acc[i][j] = 0.f;

    // staging map: slot g = p*256+tid -> row g>>3 (0..63), col4 (g&7)*4
    const int sr0 = tid >> 3;                 // rows for p=0 (0..31)
    const int sr1 = (256 + tid) >> 3;         // rows for p=1 (32..63)
    const int sc  = (tid & 7) * 4;

    for (int c = 0; c < NCH; ++c) {
        const int kc = c * KCH;

        // ---- stage h & W tiles: 4 global float4 loads, then 4 LDS writes ----
        const float4 ha = *reinterpret_cast<const float4*>(h + (size_t)(t0 + sr0) * DMOD + kc + sc);
        const float4 hb = *reinterpret_cast<const float4*>(h + (size_t)(t0 + sr1) * DMOD + kc + sc);
        const float4 wa = *reinterpret_cast<const float4*>(W + ((size_t)sr0 << 10) + kc + sc);
        const float4 wb = *reinterpret_cast<const float4*>(W + ((size_t)sr1 << 10) + kc + sc);
        *reinterpret_cast<float4*>(&h_s[sr0][sc]) = ha;
        *reinterpret_cast<float4*>(&h_s[sr1][sc]) = hb;
        *reinterpret_cast<float4*>(&w_s[sr0][sc]) = wa;
        *reinterpret_cast<float4*>(&w_s[sr1][sc]) = wb;
        __syncthreads();

        // ---- compute: 4 tokens x 4 experts; per 4-k: 8 ds_read_b128 + 64 FMA ----
#pragma unroll
        for (int k4 = 0; k4 < KCH / 4; ++k4) {
            float4 hv[4], wv[4];
#pragma unroll
            for (int i = 0; i < 4; ++i)
                hv[i] = *reinterpret_cast<const float4*>(&h_s[tt * 4 + i][k4 * 4]);
#pragma unroll
            for (int j = 0; j < 4; ++j)
                wv[j] = *reinterpret_cast<const float4*>(&w_s[ee * 4 + j][k4 * 4]);
#pragma unroll
            for (int i = 0; i < 4; ++i) {
#pragma unroll
                for (int j = 0; j < 4; ++j) {
                    float a = acc[i][j];
                    a = fmaf(hv[i].x, wv[j].x, a);
                    a = fmaf(hv[i].y, wv[j].y, a);
                    a = fmaf(hv[i].z, wv[j].z, a);
                    a = fmaf(hv[i].w, wv[j].w, a);
                    acc[i][j] = a;
                }
            }
        }
        __syncthreads();
    }

    // ---- stage logits over the (now dead) tiles ----
#pragma unroll
    for (int i = 0; i < 4; ++i)
#pragma unroll
        for (int j = 0; j < 4; ++j)
            ls[tt * 4 + i][ee * 4 + j] = acc[i][j];

    __syncthreads();

    const size_t P = (size_t)NTOK * NEXP;
    float* __restrict__ o_mask = out;
    float* __restrict__ o_prob = out + P;
    float* __restrict__ o_lc   = out + 2 * P;
    float* __restrict__ o_lsl  = out + 3 * P;
    const size_t base = (size_t)t0 * NEXP;

    // ---- vectorized writes of logits_clean / logits_sel (float4) ----
#pragma unroll
    for (int p = 0; p < 4; ++p) {
        const int g  = p * 256 + tid;         // float4 index
        const int t  = g >> 4;
        const int e4 = (g & 15) * 4;
        const float4 lv = *reinterpret_cast<const float4*>(&ls[t][e4]);
        const bool tmt = tok_mask(tmask, t0 + t, mmode);
        float4 sv;
        sv.x = tmt ? lv.x : -INFINITY;
        sv.y = tmt ? lv.y : -INFINITY;
        sv.z = tmt ? lv.z : -INFINITY;
        sv.w = tmt ? lv.w : -INFINITY;
        *reinterpret_cast<float4*>(&o_lc[base + (size_t)g * 4])  = lv;
        *reinterpret_cast<float4*>(&o_lsl[base + (size_t)g * 4]) = sv;
    }

    // ---- epilogue: wave0, one token per lane; 8-pass selection-sort top-k ----
    if (wave == 0) {
        const int lt = lane;
        const bool tm = tok_mask(tmask, t0 + lt, mmode);

        unsigned long long bits = 0ULL;
        float m0 = -INFINITY;
        for (int r = 0; r < TOPK; ++r) {
            float bv = -INFINITY; int bi = 0;
            for (int e = 0; e < 64; ++e) {
                if ((bits >> e) & 1ULL) continue;
                const float x = ls[lt][e];
                if (x > bv) { bv = x; bi = e; }
            }
            bits |= 1ULL << bi;
            if (r == 0) m0 = bv;
        }

        float ssum = 0.f;
        for (int e = 0; e < 64; ++e)
            if ((bits >> e) & 1ULL) ssum += expf(ls[lt][e] - m0);

        sm_m0[lt]  = m0;
        sm_inv[lt] = 1.0f / ssum;
        mb[lt] = tm ? bits : 0ULL;            // mb==0 encodes masked token
    }

    __syncthreads();

    // ---- vectorized writes of probs / mask (float4) ----
#pragma unroll
    for (int p = 0; p < 4; ++p) {
        const int g  = p * 256 + tid;
        const int t  = g >> 4;
        const int e4 = (g & 15) * 4;
        const float4 lv = *reinterpret_cast<const float4*>(&ls[t][e4]);
        const unsigned long long bt = mb[t];
        const float m0 = sm_m0[t], inv = sm_inv[t];
        float4 pv, mv;
        const bool s0 = (bt >> (e4 + 0)) & 1ULL;
        const bool s1 = (bt >> (e4 + 1)) & 1ULL;
        const bool s2 = (bt >> (e4 + 2)) & 1ULL;
        const bool s3 = (bt >> (e4 + 3)) & 1ULL;
        pv.x = s0 ? expf(lv.x - m0) * inv : 0.f;
        pv.y = s1 ? expf(lv.y - m0) * inv : 0.f;
        pv.z = s2 ? expf(lv.z - m0) * inv : 0.f;
        pv.w = s3 ? expf(lv.w - m0) * inv : 0.f;
        mv.x = s0 ? 1.f : 0.f;
        mv.y = s1 ? 1.f : 0.f;
        mv.z = s2 ? 1.f : 0.f;
        mv.w = s3 ? 1.f : 0.f;
        *reinterpret_cast<float4*>(&o_prob[base + (size_t)g * 4]) = pv;
        *reinterpret_cast<float4*>(&o_mask[base + (size_t)g * 4]) = mv;
    }
}

extern "C" void kernel_launch(void* const* d_in, const int* in_sizes, int n_in,
                              void* d_out, int out_size, void* d_ws, size_t ws_size,
                              hipStream_t stream)
{
    const float* h = (const float*)d_in[0];
    const float* W = (const float*)d_in[1];
    const void*  tmask = (const void*)d_in[2];
    float* out = (float*)d_out;

    hipLaunchKernelGGL(router_v14, dim3(NTOK / BTOK), dim3(256), 0, stream,
                       h, W, tmask, out);
}